// Round 4
// baseline (297.339 us; speedup 1.0000x reference)
//
#include <hip/hip_runtime.h>
#include <math.h>

#define B     4096
#define ND    13
#define NS    26
#define NF    39
#define VOCAB 100000
#define NP    351      // l<=m pairs in 26x26
#define NPP   360      // padded to 6 waves * 60
#define CHW   60       // p-chunk per wave
#define RPB   8        // rows per block
#define XSS   212      // xs row stride in floats (bank-friendly, float4-aligned)

// ---------------- workspace layout (floats) ----------------
#define OFF_V    0        // 3328
#define OFF_A1S  3328     // 360 (pad zeroed)
#define OFF_LUT  3688     // 360 ints (pad zeroed)
#define OFF_GS   4048     // 26*360 = 9360 (pads zeroed)
#define OFF_C2J  13408    // 26
#define OFF_CST  13440    // 1

// ---- precompute A: v, A1s+lut, cst (parallel, coalesced) ----
__global__ __launch_bounds__(256) void k_pre_a(const float* __restrict__ W0,
                                               const float* __restrict__ W1,
                                               const float* __restrict__ b0,
                                               const float* __restrict__ b1,
                                               const float* __restrict__ clw,
                                               float* __restrict__ v,
                                               float* __restrict__ A1s,
                                               int* __restrict__ lut,
                                               float* __restrict__ cst) {
    int blk = blockIdx.x, tid = threadIdx.x;
    if (blk < 13) {
        int q = blk * 256 + tid;                 // 13*256 = 3328 exactly
        float acc = 0.f;
#pragma unroll 8
        for (int o = 0; o < 128; o++) acc += clw[128 + o] * W1[o * 3328 + q];
        v[q] = acc;
    } else if (blk < 15) {
        int p = (blk - 13) * 256 + tid;
        if (p < NPP) {
            if (p < NP) {
                int l = 0, rem = p;
                while (rem >= NS - l) { rem -= NS - l; l++; }
                int m = l + rem;
                float sym = (l != m) ? 1.f : 0.f;
                float acc = 0.f;
#pragma unroll 8
                for (int o = 0; o < 128; o++)
                    acc += clw[o] * (W0[o * 676 + l * 26 + m] + sym * W0[o * 676 + m * 26 + l]);
                A1s[p] = acc;
                lut[p] = (l << 5) | m;
            } else {
                A1s[p] = 0.f;
                lut[p] = 0;
            }
        }
    } else {
        __shared__ float red[2];
        float c = 0.f;
        if (tid < 128) c = clw[tid] * b0[tid] + clw[128 + tid] * b1[tid];
        for (int off = 32; off; off >>= 1) c += __shfl_down(c, off, 64);
        if (tid < 128 && (tid & 63) == 0) red[tid >> 6] = c;
        __syncthreads();
        if (tid == 0) cst[0] = 8.f * (red[0] + red[1]);
    }
}

// ---- precompute B: Gs (one block per j), c2j ----
__global__ __launch_bounds__(256) void k_pre_b(const float* __restrict__ W0,
                                               const float* __restrict__ b0,
                                               const float* __restrict__ v,
                                               const int* __restrict__ lut,
                                               float* __restrict__ Gs,
                                               float* __restrict__ c2j) {
    int blk = blockIdx.x, tid = threadIdx.x;
    if (blk < 26) {
        int j = blk;
        __shared__ float vj[128];
        if (tid < 128) vj[tid] = v[tid * 26 + j];
        __syncthreads();
        for (int p = tid; p < NPP; p += 256) {
            float g = 0.f;
            if (p < NP) {
                int lm = lut[p];
                int l = lm >> 5, m = lm & 31;
                float sym = (l != m) ? 1.f : 0.f;
                int o1 = l * 26 + m, o2 = m * 26 + l;
#pragma unroll 8
                for (int i = 0; i < 128; i++)
                    g += vj[i] * (W0[i * 676 + o1] + sym * W0[i * 676 + o2]);
            }
            Gs[j * NPP + p] = g;
        }
    } else {
        if (tid < 26) {
            float acc = 0.f;
#pragma unroll 8
            for (int i = 0; i < 128; i++) acc += v[i * 26 + tid] * b0[i];
            c2j[tid] = acc;
        }
    }
}

// ---- fully fused main: gather + linear + CIN(reg) + DNN, 8 rows/block ----
__global__ __launch_bounds__(384, 3) void k_main(
    const float* __restrict__ inputs, const float* __restrict__ tables,
    const float* __restrict__ lW, const float* __restrict__ lb,
    const float* __restrict__ Gs, const float* __restrict__ A1s,
    const int* __restrict__ lut, const float* __restrict__ c2j,
    const float* __restrict__ cst,
    const float* __restrict__ dW1, const float* __restrict__ db1,
    const float* __restrict__ dW2, const float* __restrict__ db2,
    const float* __restrict__ dW3, const float* __restrict__ db3,
    const float* __restrict__ dW4, const float* __restrict__ db4,
    const float* __restrict__ clb,
    float* __restrict__ out) {
    __shared__ float insf[RPB][40];
    __shared__ float xs[RPB][XSS];        // emb per row (CIN layout, padded stride)
    __shared__ float inT[256][RPB];       // DNN input transposed; reused for partials
    __shared__ float h1T[256][RPB];
    __shared__ float h2T[128][RPB];
    __shared__ float h3T[64][RPB];
    __shared__ float lin_s[RPB], scin_s[RPB];
    __shared__ float redbuf[6][RPB];
    float* inF = &inT[0][0];

    int tid = threadIdx.x;
    int b0r = blockIdx.x * RPB;

    // phase 1: raw inputs
    for (int t = tid; t < RPB * NF; t += 384) {
        int r = t / NF, c = t - r * NF;
        insf[r][c] = inputs[(b0r + r) * NF + c];
    }
    __syncthreads();

    // phase 2: gather embeddings (both layouts) + dense cols + linear
    for (int t = tid; t < RPB * NS; t += 384) {
        int r = t / NS, f = t - r * NS;
        int idx = (int)insf[r][ND + f];
        const float4* src = (const float4*)(tables + ((long)f * VOCAB + idx) * 8);
        float4 a = src[0], b4 = src[1];
        float4* dst = (float4*)&xs[r][f * 8];
        dst[0] = a; dst[1] = b4;
        int cb = ND + f * 8;
        inT[cb + 0][r] = a.x;  inT[cb + 1][r] = a.y;
        inT[cb + 2][r] = a.z;  inT[cb + 3][r] = a.w;
        inT[cb + 4][r] = b4.x; inT[cb + 5][r] = b4.y;
        inT[cb + 6][r] = b4.z; inT[cb + 7][r] = b4.w;
    }
    for (int t = tid; t < RPB * ND; t += 384) {
        int r = t / ND, c = t - r * ND;
        inT[c][r] = insf[r][c];
    }
    if (tid < RPB) {
        float acc = lb[0];
        for (int c = 0; c < NF; c++) acc += insf[tid][c] * lW[c];
        lin_s[tid] = acc;
    }
    __syncthreads();

    // phase 3: CIN, register-resident. lane=(r,k), wave owns 60-wide p-chunk.
    {
        int lane = tid & 63, w = tid >> 6;
        int r = lane >> 3, k = lane & 7;
        const float* xrow = &xs[r][0];
        float x26[26];
#pragma unroll
        for (int j = 0; j < 26; j++) x26[j] = xrow[j * 8 + k];
        const float* gbase = Gs + w * CHW;
        float y[CHW];
#pragma unroll
        for (int p = 0; p < CHW; p++) y[p] = 0.f;
#pragma unroll
        for (int j = 0; j < 26; j++) {
            const float4* g4 = (const float4*)(gbase + j * NPP);
            float xv = x26[j];
#pragma unroll
            for (int p4 = 0; p4 < 15; p4++) {
                float4 g = g4[p4];
                y[p4 * 4 + 0] += g.x * xv; y[p4 * 4 + 1] += g.y * xv;
                y[p4 * 4 + 2] += g.z * xv; y[p4 * 4 + 3] += g.w * xv;
            }
        }
        const float4* a4 = (const float4*)(A1s + w * CHW);
        const int4* l4 = (const int4*)(lut + w * CHW);
        float part = 0.f;
#pragma unroll
        for (int p4 = 0; p4 < 15; p4++) {
            float4 a = a4[p4];
            int4 lm = l4[p4];
            { int l = lm.x >> 5, m = lm.x & 31;
              part += (a.x + y[p4 * 4 + 0]) * xrow[l * 8 + k] * xrow[m * 8 + k]; }
            { int l = lm.y >> 5, m = lm.y & 31;
              part += (a.y + y[p4 * 4 + 1]) * xrow[l * 8 + k] * xrow[m * 8 + k]; }
            { int l = lm.z >> 5, m = lm.z & 31;
              part += (a.z + y[p4 * 4 + 2]) * xrow[l * 8 + k] * xrow[m * 8 + k]; }
            { int l = lm.w >> 5, m = lm.w & 31;
              part += (a.w + y[p4 * 4 + 3]) * xrow[l * 8 + k] * xrow[m * 8 + k]; }
        }
        if (w == 0) {
#pragma unroll
            for (int j = 0; j < 26; j++) part += c2j[j] * x26[j];
        }
        part += __shfl_xor(part, 1, 64);
        part += __shfl_xor(part, 2, 64);
        part += __shfl_xor(part, 4, 64);
        if (k == 0) redbuf[w][r] = part;
    }
    __syncthreads();

    // phase 4: scin finalize + DNN layer1 (221 -> 256)
    if (tid < RPB) {
        float s = cst[0];
        for (int w = 0; w < 6; w++) s += redbuf[w][tid];
        scin_s[tid] = s;
    }
    if (tid < 256) {
        int o = tid;
        float bias = db1[o];
        float a[RPB];
#pragma unroll
        for (int r = 0; r < RPB; r++) a[r] = bias;
        for (int c = 0; c < 221; c++) {
            float w = dW1[c * 256 + o];
            const float4* iv = (const float4*)&inT[c][0];
            float4 i0 = iv[0], i1 = iv[1];
            a[0] += i0.x * w; a[1] += i0.y * w; a[2] += i0.z * w; a[3] += i0.w * w;
            a[4] += i1.x * w; a[5] += i1.y * w; a[6] += i1.z * w; a[7] += i1.w * w;
        }
        float4 o0, o1;
        o0.x = fmaxf(a[0], 0.f); o0.y = fmaxf(a[1], 0.f);
        o0.z = fmaxf(a[2], 0.f); o0.w = fmaxf(a[3], 0.f);
        o1.x = fmaxf(a[4], 0.f); o1.y = fmaxf(a[5], 0.f);
        o1.z = fmaxf(a[6], 0.f); o1.w = fmaxf(a[7], 0.f);
        float4* hv = (float4*)&h1T[o][0];
        hv[0] = o0; hv[1] = o1;
    }
    __syncthreads();

    // phase 5: layer2 (256 -> 128), split-K x2
    if (tid < 256) {
        int o = tid & 127, cg = tid >> 7;
        float bias = (cg == 0) ? db2[o] : 0.f;
        float a[RPB];
#pragma unroll
        for (int r = 0; r < RPB; r++) a[r] = bias;
        for (int c = cg * 128; c < cg * 128 + 128; c++) {
            float w = dW2[c * 128 + o];
            const float4* iv = (const float4*)&h1T[c][0];
            float4 i0 = iv[0], i1 = iv[1];
            a[0] += i0.x * w; a[1] += i0.y * w; a[2] += i0.z * w; a[3] += i0.w * w;
            a[4] += i1.x * w; a[5] += i1.y * w; a[6] += i1.z * w; a[7] += i1.w * w;
        }
        float4* pv = (float4*)&inF[tid * 8];
        pv[0] = make_float4(a[0], a[1], a[2], a[3]);
        pv[1] = make_float4(a[4], a[5], a[6], a[7]);
    }
    __syncthreads();
    if (tid < 128) {
        const float4* p0 = (const float4*)&inF[tid * 8];
        const float4* p1 = (const float4*)&inF[(tid + 128) * 8];
        float4 a0 = p0[0], a1 = p0[1], b0v = p1[0], b1v = p1[1];
        float4 o0, o1;
        o0.x = fmaxf(a0.x + b0v.x, 0.f); o0.y = fmaxf(a0.y + b0v.y, 0.f);
        o0.z = fmaxf(a0.z + b0v.z, 0.f); o0.w = fmaxf(a0.w + b0v.w, 0.f);
        o1.x = fmaxf(a1.x + b1v.x, 0.f); o1.y = fmaxf(a1.y + b1v.y, 0.f);
        o1.z = fmaxf(a1.z + b1v.z, 0.f); o1.w = fmaxf(a1.w + b1v.w, 0.f);
        float4* hv = (float4*)&h2T[tid][0];
        hv[0] = o0; hv[1] = o1;
    }
    __syncthreads();

    // phase 6: layer3 (128 -> 64), split-K x4
    if (tid < 256) {
        int o = tid & 63, cg = tid >> 6;
        float bias = (cg == 0) ? db3[o] : 0.f;
        float a[RPB];
#pragma unroll
        for (int r = 0; r < RPB; r++) a[r] = bias;
        for (int c = cg * 32; c < cg * 32 + 32; c++) {
            float w = dW3[c * 64 + o];
            const float4* iv = (const float4*)&h2T[c][0];
            float4 i0 = iv[0], i1 = iv[1];
            a[0] += i0.x * w; a[1] += i0.y * w; a[2] += i0.z * w; a[3] += i0.w * w;
            a[4] += i1.x * w; a[5] += i1.y * w; a[6] += i1.z * w; a[7] += i1.w * w;
        }
        float4* pv = (float4*)&inF[tid * 8];
        pv[0] = make_float4(a[0], a[1], a[2], a[3]);
        pv[1] = make_float4(a[4], a[5], a[6], a[7]);
    }
    __syncthreads();
    if (tid < 64) {
        float s[RPB];
#pragma unroll
        for (int r = 0; r < RPB; r++) s[r] = 0.f;
#pragma unroll
        for (int cg = 0; cg < 4; cg++) {
            const float4* pv = (const float4*)&inF[(cg * 64 + tid) * 8];
            float4 p0 = pv[0], p1 = pv[1];
            s[0] += p0.x; s[1] += p0.y; s[2] += p0.z; s[3] += p0.w;
            s[4] += p1.x; s[5] += p1.y; s[6] += p1.z; s[7] += p1.w;
        }
        float4 o0, o1;
        o0.x = fmaxf(s[0], 0.f); o0.y = fmaxf(s[1], 0.f);
        o0.z = fmaxf(s[2], 0.f); o0.w = fmaxf(s[3], 0.f);
        o1.x = fmaxf(s[4], 0.f); o1.y = fmaxf(s[5], 0.f);
        o1.z = fmaxf(s[6], 0.f); o1.w = fmaxf(s[7], 0.f);
        float4* hv = (float4*)&h3T[tid][0];
        hv[0] = o0; hv[1] = o1;
    }
    __syncthreads();

    // phase 7: layer4 + combine + sigmoid
    if (tid < 64) {
        float w4 = dW4[tid];
        const float4* hv = (const float4*)&h3T[tid][0];
        float4 v0 = hv[0], v1 = hv[1];
        float s[RPB] = { v0.x * w4, v0.y * w4, v0.z * w4, v0.w * w4,
                         v1.x * w4, v1.y * w4, v1.z * w4, v1.w * w4 };
#pragma unroll
        for (int off = 1; off < 64; off <<= 1)
#pragma unroll
            for (int r = 0; r < RPB; r++) s[r] += __shfl_xor(s[r], off, 64);
        if (tid < RPB) {
            float dense = fmaxf(s[tid] + db4[0], 0.f);
            float cin = fmaxf(scin_s[tid] + clb[0], 0.f);
            float x = lin_s[tid] + cin + dense;
            out[b0r + tid] = 1.f / (1.f + expf(-x));
        }
    }
}

extern "C" void kernel_launch(void* const* d_in, const int* in_sizes, int n_in,
                              void* d_out, int out_size, void* d_ws, size_t ws_size,
                              hipStream_t stream) {
    const float* inputs = (const float*)d_in[0];
    const float* tables = (const float*)d_in[1];
    const float* lW     = (const float*)d_in[2];
    const float* lb     = (const float*)d_in[3];
    const float* W0     = (const float*)d_in[4];
    const float* b0     = (const float*)d_in[5];
    const float* W1c    = (const float*)d_in[6];
    const float* b1c    = (const float*)d_in[7];
    const float* clw    = (const float*)d_in[8];
    const float* clb    = (const float*)d_in[9];
    const float* dW1    = (const float*)d_in[10];
    const float* db1    = (const float*)d_in[11];
    const float* dW2    = (const float*)d_in[12];
    const float* db2    = (const float*)d_in[13];
    const float* dW3    = (const float*)d_in[14];
    const float* db3    = (const float*)d_in[15];
    const float* dW4    = (const float*)d_in[16];
    const float* db4    = (const float*)d_in[17];

    float* ws   = (float*)d_ws;
    float* v    = ws + OFF_V;
    float* A1s  = ws + OFF_A1S;
    int*   lut  = (int*)(ws + OFF_LUT);
    float* Gs   = ws + OFF_GS;
    float* c2j  = ws + OFF_C2J;
    float* cst  = ws + OFF_CST;

    k_pre_a<<<16, 256, 0, stream>>>(W0, W1c, b0, b1c, clw, v, A1s, lut, cst);
    k_pre_b<<<27, 256, 0, stream>>>(W0, b0, v, lut, Gs, c2j);
    k_main<<<B / RPB, 384, 0, stream>>>(inputs, tables, lW, lb, Gs, A1s, lut, c2j, cst,
                                        dW1, db1, dW2, db2, dW3, db3, dW4, db4, clb,
                                        (float*)d_out);
}

// Round 5
// 227.858 us; speedup vs baseline: 1.3049x; 1.3049x over previous
//
#include <hip/hip_runtime.h>
#include <math.h>

#define B     4096
#define ND    13
#define NS    26
#define NF    39
#define VOCAB 100000
#define NP    351      // l<=m pairs in 26x26
#define NPP   360      // padded to 8 chunks * 45
#define CHP   45       // p's per chunk (8 chunks: 4 waves x 2 half-waves)
#define GSTR  28       // Gst row: [0..25]=Gs_j, [26]=A1s, [27]=lut bits
#define RPB   4
#define XSS   212

// ---------------- workspace layout (floats) ----------------
#define OFF_GST 0        // 360*28 = 10080
#define OFF_CST 10080    // 1
#define OFF_C2J 10088    // 26

// ---- single merged precompute kernel, 28 independent blocks ----
__global__ __launch_bounds__(256) void k_pre(const float* __restrict__ W0,
                                             const float* __restrict__ W1,
                                             const float* __restrict__ b0,
                                             const float* __restrict__ b1,
                                             const float* __restrict__ clw,
                                             float* __restrict__ Gst,
                                             float* __restrict__ cst,
                                             float* __restrict__ c2j) {
    int blk = blockIdx.x, tid = threadIdx.x;
    if (blk < 26) {
        // block j: v[:,j] in LDS, then Gst[p][j] for all p, plus c2j[j]
        int j = blk;
        __shared__ float vh[2][128];
        __shared__ float vj[128];
        __shared__ float c2r[2];
        {
            int i = tid & 127, h = tid >> 7;
            const float* wp = W1 + (long)(h * 64) * 3328 + i * 26 + j;
            float acc = 0.f;
#pragma unroll 8
            for (int o = 0; o < 64; o++) acc += clw[128 + h * 64 + o] * wp[o * 3328];
            vh[h][i] = acc;
        }
        __syncthreads();
        if (tid < 128) {
            float vv = vh[0][tid] + vh[1][tid];
            vj[tid] = vv;
            float c = vv * b0[tid];
            for (int off = 32; off; off >>= 1) c += __shfl_down(c, off, 64);
            if ((tid & 63) == 0) c2r[tid >> 6] = c;
        }
        __syncthreads();
        if (tid == 0) c2j[j] = c2r[0] + c2r[1];
        for (int p = tid; p < NPP; p += 256) {
            float g = 0.f;
            if (p < NP) {
                int l = 0, rem = p;
                while (rem >= NS - l) { rem -= NS - l; l++; }
                int m = l + rem;
                float sym = (l != m) ? 1.f : 0.f;
                const float* wa = W0 + l * 26 + m;
                const float* wb = W0 + m * 26 + l;
#pragma unroll 8
                for (int i = 0; i < 128; i++)
                    g += vj[i] * (wa[i * 676] + sym * wb[i * 676]);
            }
            Gst[p * GSTR + j] = g;
        }
    } else if (blk == 26) {
        // A1s (slot 26) + lut bits (slot 27)
        for (int p = tid; p < NPP; p += 256) {
            float a = 0.f; int lmbits = 0;
            if (p < NP) {
                int l = 0, rem = p;
                while (rem >= NS - l) { rem -= NS - l; l++; }
                int m = l + rem;
                float sym = (l != m) ? 1.f : 0.f;
                const float* wa = W0 + l * 26 + m;
                const float* wb = W0 + m * 26 + l;
#pragma unroll 8
                for (int o = 0; o < 128; o++)
                    a += clw[o] * (wa[o * 676] + sym * wb[o * 676]);
                lmbits = (l << 5) | m;
            }
            Gst[p * GSTR + 26] = a;
            Gst[p * GSTR + 27] = __int_as_float(lmbits);
        }
    } else {
        __shared__ float red[2];
        float c = 0.f;
        if (tid < 128) {
            c = clw[tid] * b0[tid] + clw[128 + tid] * b1[tid];
            for (int off = 32; off; off >>= 1) c += __shfl_down(c, off, 64);
            if ((tid & 63) == 0) red[tid >> 6] = c;
        }
        __syncthreads();
        if (tid == 0) cst[0] = 8.f * (red[0] + red[1]);
    }
}

// ---- fused main: gather + linear + CIN (t-form, 27 accs) + DNN, 4 rows/block ----
__global__ __launch_bounds__(256, 4) void k_main(
    const float* __restrict__ inputs, const float* __restrict__ tables,
    const float* __restrict__ lW, const float* __restrict__ lb,
    const float* __restrict__ Gst, const float* __restrict__ c2j,
    const float* __restrict__ cst,
    const float* __restrict__ dW1, const float* __restrict__ db1,
    const float* __restrict__ dW2, const float* __restrict__ db2,
    const float* __restrict__ dW3, const float* __restrict__ db3,
    const float* __restrict__ dW4, const float* __restrict__ db4,
    const float* __restrict__ clb,
    float* __restrict__ out) {
    __shared__ float insf[RPB][40];
    __shared__ float xs[RPB][XSS];       // emb per row, CIN layout
    __shared__ float inT[256][RPB];      // DNN input transposed; reused as partial buf
    __shared__ float h1T[256][RPB];
    __shared__ float h2T[128][RPB];
    __shared__ float lin_s[RPB], scin_s[RPB];
    __shared__ float redbuf[4][RPB];
    float* inF = &inT[0][0];             // 1024 floats flat

    int tid = threadIdx.x;
    int b0r = blockIdx.x * RPB;

    // phase 1: raw inputs
    for (int t = tid; t < RPB * NF; t += 256) {
        int r = t / NF, c = t - r * NF;
        insf[r][c] = inputs[(b0r + r) * NF + c];
    }
    __syncthreads();

    // phase 2: gather embeddings (both layouts) + dense cols + linear term
    if (tid < RPB * NS) {
        int r = tid / NS, f = tid - r * NS;
        int idx = (int)insf[r][ND + f];
        const float4* src = (const float4*)(tables + ((long)f * VOCAB + idx) * 8);
        float4 a = src[0], b4 = src[1];
        float4* dst = (float4*)&xs[r][f * 8];
        dst[0] = a; dst[1] = b4;
        int cb = ND + f * 8;
        inT[cb + 0][r] = a.x;  inT[cb + 1][r] = a.y;
        inT[cb + 2][r] = a.z;  inT[cb + 3][r] = a.w;
        inT[cb + 4][r] = b4.x; inT[cb + 5][r] = b4.y;
        inT[cb + 6][r] = b4.z; inT[cb + 7][r] = b4.w;
    }
    if (tid >= 128 && tid < 128 + RPB * ND) {
        int t = tid - 128;
        int r = t / ND, c = t - r * ND;
        inT[c][r] = insf[r][c];
    }
    if (tid >= 192 && tid < 192 + RPB) {
        int r = tid - 192;
        float acc = lb[0];
        for (int c = 0; c < NF; c++) acc += insf[r][c] * lW[c];
        lin_s[r] = acc;
    }
    __syncthreads();

    // phase 3: CIN, t-form. lane=(pg,r,k); chunk = wave*2+pg owns 45 p's.
    {
        int lane = tid & 63, w = tid >> 6;
        int pg = lane >> 5;
        int r = (lane >> 3) & 3;
        int k = lane & 7;
        int chunk = w * 2 + pg;          // 0..7
        const float* xrow = &xs[r][0];
        float t[27];
#pragma unroll
        for (int j = 0; j < 27; j++) t[j] = 0.f;
        const float4* grow = (const float4*)(Gst + chunk * CHP * GSTR);
#pragma unroll 2
        for (int pi = 0; pi < CHP; pi++) {
            float4 g6 = grow[pi * 7 + 6];
            int lm = __float_as_int(g6.w);
            float q = xrow[(lm >> 5) * 8 + k] * xrow[(lm & 31) * 8 + k];
            float4 g0 = grow[pi * 7 + 0], g1 = grow[pi * 7 + 1];
            float4 g2 = grow[pi * 7 + 2], g3 = grow[pi * 7 + 3];
            float4 g4 = grow[pi * 7 + 4], g5 = grow[pi * 7 + 5];
            t[0]  += g0.x * q; t[1]  += g0.y * q; t[2]  += g0.z * q; t[3]  += g0.w * q;
            t[4]  += g1.x * q; t[5]  += g1.y * q; t[6]  += g1.z * q; t[7]  += g1.w * q;
            t[8]  += g2.x * q; t[9]  += g2.y * q; t[10] += g2.z * q; t[11] += g2.w * q;
            t[12] += g3.x * q; t[13] += g3.y * q; t[14] += g3.z * q; t[15] += g3.w * q;
            t[16] += g4.x * q; t[17] += g4.y * q; t[18] += g4.z * q; t[19] += g4.w * q;
            t[20] += g5.x * q; t[21] += g5.y * q; t[22] += g5.z * q; t[23] += g5.w * q;
            t[24] += g6.x * q; t[25] += g6.y * q; t[26] += g6.z * q;
        }
        float csel = (chunk == 0) ? 1.f : 0.f;
        float part = t[26];
#pragma unroll
        for (int j = 0; j < 26; j++) {
            float xv = xrow[j * 8 + k];
            part += (t[j] + csel * c2j[j]) * xv;
        }
        part += __shfl_xor(part, 1, 64);
        part += __shfl_xor(part, 2, 64);
        part += __shfl_xor(part, 4, 64);
        part += __shfl_xor(part, 32, 64);
        if ((lane & 39) == 0) redbuf[w][r] = part;   // k==0 && pg==0
    }
    __syncthreads();

    // phase 4: scin finalize + DNN layer1 (221 -> 256)
    if (tid < RPB) {
        float s = cst[0];
        for (int w = 0; w < 4; w++) s += redbuf[w][tid];
        scin_s[tid] = s;
    }
    {
        float bias = db1[tid];
        float a0 = bias, a1 = bias, a2 = bias, a3 = bias;
        for (int c = 0; c < 221; c++) {
            float wv = dW1[c * 256 + tid];
            float4 iv = *(const float4*)&inT[c][0];
            a0 += iv.x * wv; a1 += iv.y * wv; a2 += iv.z * wv; a3 += iv.w * wv;
        }
        float4 o0;
        o0.x = fmaxf(a0, 0.f); o0.y = fmaxf(a1, 0.f);
        o0.z = fmaxf(a2, 0.f); o0.w = fmaxf(a3, 0.f);
        *(float4*)&h1T[tid][0] = o0;
    }
    __syncthreads();

    // phase 5: layer2 (256 -> 128), split-K x2
    {
        int o = tid & 127, cg = tid >> 7;
        float bias = (cg == 0) ? db2[o] : 0.f;
        float a0 = bias, a1 = bias, a2 = bias, a3 = bias;
        const float* wbase = dW2 + cg * 128 * 128 + o;
        const float* hbase = &h1T[cg * 128][0];
        for (int c = 0; c < 128; c++) {
            float wv = wbase[c * 128];
            float4 iv = *(const float4*)(hbase + c * RPB);
            a0 += iv.x * wv; a1 += iv.y * wv; a2 += iv.z * wv; a3 += iv.w * wv;
        }
        *(float4*)&inF[tid * 4] = make_float4(a0, a1, a2, a3);
    }
    __syncthreads();
    if (tid < 128) {
        float4 p0 = *(const float4*)&inF[tid * 4];
        float4 p1 = *(const float4*)&inF[(tid + 128) * 4];
        float4 o0;
        o0.x = fmaxf(p0.x + p1.x, 0.f); o0.y = fmaxf(p0.y + p1.y, 0.f);
        o0.z = fmaxf(p0.z + p1.z, 0.f); o0.w = fmaxf(p0.w + p1.w, 0.f);
        *(float4*)&h2T[tid][0] = o0;
    }
    __syncthreads();

    // phase 6: layer3 (128 -> 64), split-K x4
    {
        int o = tid & 63, cg = tid >> 6;
        float bias = (cg == 0) ? db3[o] : 0.f;
        float a0 = bias, a1 = bias, a2 = bias, a3 = bias;
        const float* wbase = dW3 + cg * 32 * 64 + o;
        const float* hbase = &h2T[cg * 32][0];
        for (int c = 0; c < 32; c++) {
            float wv = wbase[c * 64];
            float4 iv = *(const float4*)(hbase + c * RPB);
            a0 += iv.x * wv; a1 += iv.y * wv; a2 += iv.z * wv; a3 += iv.w * wv;
        }
        *(float4*)&inF[tid * 4] = make_float4(a0, a1, a2, a3);
    }
    __syncthreads();

    // phase 7: combine L3 + layer4 (64 -> 1) + final combine + sigmoid
    if (tid < 64) {
        float s0 = 0.f, s1 = 0.f, s2 = 0.f, s3 = 0.f;
#pragma unroll
        for (int cg = 0; cg < 4; cg++) {
            float4 pv = *(const float4*)&inF[(cg * 64 + tid) * 4];
            s0 += pv.x; s1 += pv.y; s2 += pv.z; s3 += pv.w;
        }
        float w4 = dW4[tid];
        s0 = fmaxf(s0, 0.f) * w4; s1 = fmaxf(s1, 0.f) * w4;
        s2 = fmaxf(s2, 0.f) * w4; s3 = fmaxf(s3, 0.f) * w4;
#pragma unroll
        for (int off = 1; off < 64; off <<= 1) {
            s0 += __shfl_xor(s0, off, 64);
            s1 += __shfl_xor(s1, off, 64);
            s2 += __shfl_xor(s2, off, 64);
            s3 += __shfl_xor(s3, off, 64);
        }
        if (tid == 0) {
            float sv[4] = { s0, s1, s2, s3 };
            float bb = db4[0], cb = clb[0];
#pragma unroll
            for (int r = 0; r < RPB; r++) {
                float dense = fmaxf(sv[r] + bb, 0.f);
                float cin = fmaxf(scin_s[r] + cb, 0.f);
                float x = lin_s[r] + cin + dense;
                out[b0r + r] = 1.f / (1.f + expf(-x));
            }
        }
    }
}

extern "C" void kernel_launch(void* const* d_in, const int* in_sizes, int n_in,
                              void* d_out, int out_size, void* d_ws, size_t ws_size,
                              hipStream_t stream) {
    const float* inputs = (const float*)d_in[0];
    const float* tables = (const float*)d_in[1];
    const float* lW     = (const float*)d_in[2];
    const float* lb     = (const float*)d_in[3];
    const float* W0     = (const float*)d_in[4];
    const float* b0     = (const float*)d_in[5];
    const float* W1c    = (const float*)d_in[6];
    const float* b1c    = (const float*)d_in[7];
    const float* clw    = (const float*)d_in[8];
    const float* clb    = (const float*)d_in[9];
    const float* dW1    = (const float*)d_in[10];
    const float* db1    = (const float*)d_in[11];
    const float* dW2    = (const float*)d_in[12];
    const float* db2    = (const float*)d_in[13];
    const float* dW3    = (const float*)d_in[14];
    const float* db3    = (const float*)d_in[15];
    const float* dW4    = (const float*)d_in[16];
    const float* db4    = (const float*)d_in[17];

    float* ws   = (float*)d_ws;
    float* Gst  = ws + OFF_GST;
    float* cst  = ws + OFF_CST;
    float* c2j  = ws + OFF_C2J;

    k_pre<<<28, 256, 0, stream>>>(W0, W1c, b0, b1c, clw, Gst, cst, c2j);
    k_main<<<B / RPB, 256, 0, stream>>>(inputs, tables, lW, lb, Gst, c2j, cst,
                                        dW1, db1, dW2, db2, dW3, db3, dW4, db4, clb,
                                        (float*)d_out);
}